// Round 14
// baseline (96.657 us; speedup 1.0000x reference)
//
#include <hip/hip_runtime.h>
#include <float.h>

#define B_CONST 8
#define ONE_BF 0x3F80          // bf16(1.0)

typedef short short8 __attribute__((ext_vector_type(8)));
typedef float f32x4  __attribute__((ext_vector_type(4)));

__device__ __forceinline__ unsigned short f2bf(float f) {   // RNE f32->bf16
    unsigned u = __float_as_uint(f);
    return (unsigned short)((u + 0x7FFFu + ((u >> 16) & 1u)) >> 16);
}
__device__ __forceinline__ float bf2f(unsigned short h) {
    return __uint_as_float(((unsigned)h) << 16);
}
__device__ __forceinline__ float min3(float a, float b, float c) {
    float d;
    asm("v_min3_f32 %0, %1, %2, %3" : "=v"(d) : "v"(a), "v"(b), "v"(c));
    return d;
}

// Single-pass MFMA kernel: block = 128 queries (rows) x 1024 refs (cols) of one
// batch's d-matrix. K-slot packing makes ONE mfma_f32_16x16x32_bf16 emit a
// 16x16 tile of COMPLETE d = qw + rw - 2 q.r in split-bf16 precision:
//   k0-2:(-2hq)(hr)  k3-5:(-2eq)(hr)  k6-8:(hq)(-2er)   -> -2 q.r (+O(e*e))
//   k9-10:(1,1)(h_rw,e_rw) -> +rw     k11-12:(hqw,eqw)(1,1) -> +qw
// Row-mins (dist1) accumulate in regs per lane (C col=lane&15 fixed, verified
// m89); col-mins (dist2) tree-reduce the 4 regs -> LDS atomicMin. Both
// directions from ONE pass -- halves the work vs all previous rounds.
__global__ __launch_bounds__(256) void hd_mfma(
    const float* __restrict__ p1, const float* __restrict__ p2,
    float* __restrict__ part_row, float* __restrict__ part_col,
    unsigned int* __restrict__ comm, int N, int M) {
    int t = threadIdx.x;
    int blk = blockIdx.x;
    if (blk == 0 && t < 9) comm[t] = 0u;

    int gCount  = M >> 10;               // 1024-ref col groups
    int rbCount = N >> 7;                // 128-query row blocks
    int perB = rbCount * gCount;
    int b   = blk / perB;
    int rem = blk - b * perB;
    int rb  = rem / gCount;
    int g   = rem - rb * gCount;

    __shared__ unsigned short ldsBlo[8192];   // B-frag k0-7  [tile][ref][8] 16KB
    __shared__ unsigned short ldsBhi[8192];   // B-frag k8-15 16KB
    __shared__ unsigned short ldsA0[1024];    // A-frag k0-7 per query 2KB
    __shared__ unsigned short ldsA1[512];     // [hz,hqw,eqw,0] per query 1KB
    __shared__ unsigned int   ldsColU[1024];  // col-min bits 4KB
    __shared__ float          ldsRow[128];
    __shared__ unsigned short ldsZero[8];

    // ---- prep: convert this block's refs+queries to ready-to-load fragments
    if (t < 8) ldsZero[t] = 0;
    for (int i = t; i < 1024; i += 256) ldsColU[i] = 0x7F7FFFFFu;

    const float* rsrc = p2 + 3 * ((size_t)b * M + ((size_t)g << 10));
    for (int i = t; i < 1024; i += 256) {
        float x = rsrc[3*i], y = rsrc[3*i+1], z = rsrc[3*i+2];
        unsigned short hx = f2bf(x), hy = f2bf(y), hz = f2bf(z);
        float ex = x - bf2f(hx), ey = y - bf2f(hy), ez = z - bf2f(hz);
        unsigned short m2ex = f2bf(-2.f*ex), m2ey = f2bf(-2.f*ey), m2ez = f2bf(-2.f*ez);
        float rw = fmaf(x,x,fmaf(y,y,z*z));
        unsigned short hrw = f2bf(rw);
        unsigned short erw = f2bf(rw - bf2f(hrw));
        unsigned* lo = (unsigned*)(ldsBlo + i*8);   // [hx,hy,hz,hx,hy,hz,-2ex,-2ey]
        lo[0] = hx | ((unsigned)hy << 16);
        lo[1] = hz | ((unsigned)hx << 16);
        lo[2] = hy | ((unsigned)hz << 16);
        lo[3] = m2ex | ((unsigned)m2ey << 16);
        unsigned* hi = (unsigned*)(ldsBhi + i*8);   // [-2ez,hrw,erw,1,1,0,0,0]
        hi[0] = m2ez | ((unsigned)hrw << 16);
        hi[1] = erw | ((unsigned)ONE_BF << 16);
        hi[2] = ONE_BF;
        hi[3] = 0;
    }
    const float* qsrc = p1 + 3 * ((size_t)b * N + ((size_t)rb << 7));
    if (t < 128) {
        float x = qsrc[3*t], y = qsrc[3*t+1], z = qsrc[3*t+2];
        unsigned short hx = f2bf(x), hy = f2bf(y), hz = f2bf(z);
        float ex = x - bf2f(hx), ey = y - bf2f(hy), ez = z - bf2f(hz);
        float qw = fmaf(x,x,fmaf(y,y,z*z));
        unsigned short hqw = f2bf(qw);
        unsigned short eqw = f2bf(qw - bf2f(hqw));
        unsigned* a0 = (unsigned*)(ldsA0 + t*8);    // [-2hx,-2hy,-2hz,-2ex,-2ey,-2ez,hx,hy]
        a0[0] = f2bf(-2.f*bf2f(hx)) | ((unsigned)f2bf(-2.f*bf2f(hy)) << 16);
        a0[1] = f2bf(-2.f*bf2f(hz)) | ((unsigned)f2bf(-2.f*ex) << 16);
        a0[2] = f2bf(-2.f*ey) | ((unsigned)f2bf(-2.f*ez) << 16);
        a0[3] = hx | ((unsigned)hy << 16);
        unsigned* a1 = (unsigned*)(ldsA1 + t*4);
        a1[0] = hz | ((unsigned)hqw << 16);
        a1[1] = eqw;
    }
    __syncthreads();

    // ---- MFMA loop: wave w covers query-strips s = w, w+4 (16 queries each)
    int l = t & 63, w = t >> 6;
    int n = l & 15, quad = l >> 4;
    const unsigned short* bbase = (quad == 0) ? (ldsBlo + n*8)
                                : (quad == 1) ? (ldsBhi + n*8) : ldsZero;
    int bstride = (quad < 2) ? 128 : 0;   // ushorts between consecutive ref-tiles

    f32x4 zacc = {0.f, 0.f, 0.f, 0.f};

    for (int s = w; s < 8; s += 4) {
        int qhat = (s << 4) + n;
        short8 af;
        {
            short8 a0v = *(const short8*)(ldsA0 + qhat*8);
            unsigned short hz_ = ldsA1[qhat*4], hqw = ldsA1[qhat*4+1], eqw = ldsA1[qhat*4+2];
            short8 ahi = { (short)hz_, (short)ONE_BF, (short)ONE_BF,
                           (short)hqw, (short)eqw, 0, 0, 0 };
            short8 az = {0,0,0,0,0,0,0,0};
            af = (quad == 0) ? a0v : (quad == 1) ? ahi : az;
        }
        float rm0 = FLT_MAX, rm1 = FLT_MAX, rm2 = FLT_MAX, rm3 = FLT_MAX;
        #pragma unroll 4
        for (int j = 0; j < 64; ++j) {
            short8 bf = *(const short8*)(bbase + j * bstride);
            f32x4 D = __builtin_amdgcn_mfma_f32_16x16x32_bf16(af, bf, zacc, 0, 0, 0);
            rm0 = fminf(rm0, D[0]); rm1 = fminf(rm1, D[1]);
            rm2 = fminf(rm2, D[2]); rm3 = fminf(rm3, D[3]);
            float cm = fminf(min3(D[0], D[1], D[2]), D[3]);
            atomicMin(&ldsColU[(j << 4) + n], __float_as_uint(cm));
        }
        // row-min: butterfly over the 16 cols (lanes within quad)
        #pragma unroll
        for (int msk = 1; msk < 16; msk <<= 1) {
            rm0 = fminf(rm0, __shfl_xor(rm0, msk, 64));
            rm1 = fminf(rm1, __shfl_xor(rm1, msk, 64));
            rm2 = fminf(rm2, __shfl_xor(rm2, msk, 64));
            rm3 = fminf(rm3, __shfl_xor(rm3, msk, 64));
        }
        if (n == 0) {                       // C/D row = quad*4 + reg (m89)
            float* rr = ldsRow + (s << 4) + (quad << 2);
            rr[0] = rm0; rr[1] = rm1; rr[2] = rm2; rr[3] = rm3;
        }
    }
    __syncthreads();

    if (t < 128)
        part_row[((size_t)g * B_CONST + b) * N + ((size_t)rb << 7) + t] =
            fmaxf(ldsRow[t], 0.f);
    for (int i = t; i < 1024; i += 256)
        part_col[((size_t)b * rbCount + rb) * M + ((size_t)g << 10) + i] =
            fmaxf(__uint_as_float(ldsColU[i]), 0.f);
}

// 128 blocks: (dir, b, query-slice). dir0: min over gCount row-partials (dist1);
// dir1: min over rbCount col-partials (dist2). max over slice -> atomicMax
// comm[b]; ticket 127 sums into out[0].
__global__ __launch_bounds__(256) void hd_final(
    const float* __restrict__ part_row, const float* __restrict__ part_col,
    unsigned int* __restrict__ comm, float* __restrict__ out, int N, int M) {
    int db  = blockIdx.x >> 3;
    int qs  = blockIdx.x & 7;
    int dir = db >> 3;
    int bb  = db & 7;
    int G   = dir ? (N >> 7) : (M >> 10);
    int QN  = dir ? M : N;
    const float* base = dir ? part_col + (size_t)bb * (N >> 7) * M
                            : part_row + (size_t)bb * N;
    size_t gstride = dir ? (size_t)M : (size_t)B_CONST * N;

    int span = QN >> 3;
    int q0 = qs * span;
    float mx = 0.f;
    for (int qq = q0 + threadIdx.x; qq < q0 + span; qq += 256) {
        float mm = base[qq];
        for (int gg = 1; gg < G; ++gg)
            mm = fminf(mm, base[(size_t)gg * gstride + qq]);
        mx = fmaxf(mx, mm);
    }
    #pragma unroll
    for (int off = 32; off > 0; off >>= 1)
        mx = fmaxf(mx, __shfl_down(mx, off, 64));
    __shared__ float wred[4];
    int l = threadIdx.x & 63, w = threadIdx.x >> 6;
    if (l == 0) wred[w] = mx;
    __syncthreads();
    if (threadIdx.x == 0) {
        mx = fmaxf(fmaxf(wred[0], wred[1]), fmaxf(wred[2], wred[3]));
        atomicMax(&comm[bb], __float_as_uint(mx));
        __threadfence();
        unsigned int t2 = atomicAdd(&comm[8], 1u);
        if (t2 == 127u) {
            float s = 0.f;
            for (int k = 0; k < B_CONST; ++k)
                s += __uint_as_float(atomicMax(&comm[k], 0u));
            out[0] = s;
        }
    }
}

extern "C" void kernel_launch(void* const* d_in, const int* in_sizes, int n_in,
                              void* d_out, int out_size, void* d_ws, size_t ws_size,
                              hipStream_t stream) {
    const float* p1 = (const float*)d_in[0];
    const float* p2 = (const float*)d_in[1];
    const int B = B_CONST;
    int N = in_sizes[0] / (3 * B);
    int M = in_sizes[1] / (3 * B);

    float* part_row = (float*)d_ws;                               // (M>>10)*B*N
    float* part_col = part_row + (size_t)(M >> 10) * B * N;       // (N>>7)*B*M
    unsigned int* comm = (unsigned int*)(part_col + (size_t)(N >> 7) * B * M);

    int blocks = B * (N >> 7) * (M >> 10);    // 1024
    hd_mfma<<<blocks, 256, 0, stream>>>(p1, p2, part_row, part_col, comm, N, M);
    hd_final<<<128, 256, 0, stream>>>(part_row, part_col, comm, (float*)d_out, N, M);
}